// Round 10
// baseline (267.505 us; speedup 1.0000x reference)
//
#include <hip/hip_runtime.h>

#define HDIM 4096
#define NIN 17
#define NA 4

using f4 = __attribute__((ext_vector_type(4))) float;

// ---- config ----
constexpr int TB = 256;                 // threads per block
constexpr int CPT = 4;                  // columns per thread (one float4)
constexpr int BXC = HDIM / (TB * CPT);  // 4 column groups
constexpr int NCHUNK = 1024;            // row chunks (4096 blocks total)
constexpr int RPC = HDIM / NCHUNK;      // 4 rows per chunk
constexpr size_t NELEM = (size_t)HDIM * HDIM;

// Kernel A: partial sums of hidden @ (w + alpha*hebb).
// CACHE-FOOTPRINT POLICY (the one variable changed vs R7):
//   alpha : NONTEMPORAL (the single sacrificial HBM stream, 64 MB/iter)
//   w     : NORMAL  -> L3-resident across iterations (NEW)
//   hebb  : NORMAL  -> L3-resident (proven: R7 FETCH 98 = w+alpha only)
// Allocated L3 set: w 64 + hebb 64 + harness re-poison ~64 + partial 16
// = ~208 MB < 256 MB L3. All-normal (R4) thrashed at 264 MB -> FETCH 197;
// two-NT (R7) pinned 128 MB/iter from HBM -> FETCH 98. This aims for ~64.
__global__ void k_matvec(const float* __restrict__ w, const float* __restrict__ alpha,
                         const float* __restrict__ hebb, const float* __restrict__ hidden,
                         float* __restrict__ partial, float* __restrict__ acc5,
                         unsigned* __restrict__ cnt) {
    if (blockIdx.x == 0 && blockIdx.y == 0 && threadIdx.x < 9) {
        if (threadIdx.x < 8) acc5[threadIdx.x] = 0.f;
        else *cnt = 0u;
    }
    const int col0 = (blockIdx.x * TB + threadIdx.x) * CPT;
    const int row0 = blockIdx.y * RPC;
    const size_t base = (size_t)row0 * HDIM + col0;

    f4 wv[RPC], av[RPC], bv[RPC];
#pragma unroll
    for (int r = 0; r < RPC; ++r) {
        const size_t off = base + (size_t)r * HDIM;
        wv[r] = *(const f4*)(w + off);                              // allocating
        av[r] = __builtin_nontemporal_load((const f4*)(alpha + off)); // streaming
        bv[r] = *(const f4*)(hebb + off);                           // allocating
    }
    f4 acc = {0.f, 0.f, 0.f, 0.f};
#pragma unroll
    for (int r = 0; r < RPC; ++r) {
        const float hv = hidden[row0 + r];
        acc += hv * (wv[r] + av[r] * bv[r]);
    }
    *(f4*)(partial + (size_t)blockIdx.y * HDIM + col0) = acc;
}

// Kernel B: reduce 1024 partials per column -> h = tanh(i2h + matvec);
// fused heads (shfl + atomicAdd) + last-block softmax/value finalize. (R7)
constexpr int HC = 32;                // cols per block
constexpr int HGRP = TB / HC;         // 8 groups
constexpr int HCPG = NCHUNK / HGRP;   // 128 chunks per group

__global__ void k_hact(const float* __restrict__ partial, const float* __restrict__ x,
                       const float* __restrict__ i2h_w, const float* __restrict__ i2h_b,
                       const float* __restrict__ h2o_w, const float* __restrict__ h2o_b,
                       const float* __restrict__ h2v_w, const float* __restrict__ h2v_b,
                       float* __restrict__ h_f, float* __restrict__ h_out,
                       float* __restrict__ acc5, unsigned* __restrict__ cnt,
                       float* __restrict__ out) {
    const int tid = threadIdx.x;
    const int lane = tid & (HC - 1);
    const int grp = tid >> 5;
    const int col = blockIdx.x * HC + lane;

    float s = 0.f;
    const float* p = partial + (size_t)(grp * HCPG) * HDIM + col;
#pragma unroll 16
    for (int c = 0; c < HCPG; ++c) s += p[(size_t)c * HDIM];

    __shared__ float red[TB];
    red[tid] = s;
    __syncthreads();
    for (int st = TB / 2; st >= HC; st >>= 1) {
        if (tid < st) red[tid] += red[tid + st];
        __syncthreads();
    }
    if (tid < HC) {
        float z = red[tid] + i2h_b[col];
#pragma unroll
        for (int k = 0; k < NIN; ++k) z += x[k] * i2h_w[col * NIN + k];
        const float h = tanhf(z);
        h_f[col] = h;
        h_out[col] = h;
        float d[NA + 1];
#pragma unroll
        for (int a = 0; a < NA; ++a) d[a] = h * h2o_w[(size_t)a * HDIM + col];
        d[NA] = h * h2v_w[col];
#pragma unroll
        for (int a = 0; a <= NA; ++a) {
            float v = d[a];
#pragma unroll
            for (int sft = 16; sft > 0; sft >>= 1) v += __shfl_down(v, sft, 32);
            if (lane == 0) atomicAdd(acc5 + a, v);
        }
    }
    // last-block finalize (R6-proven): no separate k_finish dispatch
    if (tid == 0) {
        __threadfence();
        if (atomicAdd(cnt, 1u) == (HDIM / HC) - 1) {
            float res[NA + 1];
#pragma unroll
            for (int a = 0; a <= NA; ++a) res[a] = atomicAdd(acc5 + a, 0.f);
            float o[NA];
            float mx = -1e30f;
#pragma unroll
            for (int a = 0; a < NA; ++a) { o[a] = res[a] + h2o_b[a]; mx = fmaxf(mx, o[a]); }
            float se = 0.f;
#pragma unroll
            for (int a = 0; a < NA; ++a) { o[a] = __expf(o[a] - mx); se += o[a]; }
#pragma unroll
            for (int a = 0; a < NA; ++a) out[a] = o[a] / se;
            out[NA] = res[NA] + h2v_b[0];
        }
    }
}

// Kernel C: hebb_new = (1-eta)*hebb + eta*outer(hidden, h). (R8 shuffle-realign)
// hebb read NORMAL (L3-hot from matvec); 1 aligned f4 load + 3 shfl_down +
// 1 aligned NT f4 store per 16 B of output (4t+3 alignment trick).
constexpr size_t NQK = (NELEM - 4) / 4;   // 4194303 output quads
constexpr int HEB_BLK = 4096;             // x 256 threads x 4 quads >= NQK

__global__ void k_hebb(const float* __restrict__ hebb, const float* __restrict__ hidden,
                       const float* __restrict__ h_f, const float* __restrict__ eta,
                       float* __restrict__ hebb_out) {
    const int tid = threadIdx.x;
    const size_t gt = (size_t)blockIdx.x * TB + tid;
    const size_t wid = gt >> 6;           // global wave id
    const int lane = tid & 63;
    const float e = eta[0];
    const float om = 1.f - e;

    if (gt == 0) {  // head elements 0,1,2 (row 0) + tail element NELEM-1
        const float hv0 = e * hidden[0];
        hebb_out[0] = om * hebb[0] + hv0 * h_f[0];
        hebb_out[1] = om * hebb[1] + hv0 * h_f[1];
        hebb_out[2] = om * hebb[2] + hv0 * h_f[2];
        hebb_out[NELEM - 1] = om * hebb[NELEM - 1] + e * hidden[HDIM - 1] * h_f[HDIM - 1];
    }

    size_t k[4];
    bool ok[4];
    f4 A[4];
#pragma unroll
    for (int q = 0; q < 4; ++q) {
        k[q] = wid * 256 + (size_t)lane + (size_t)q * 64;
        ok[q] = k[q] < NQK;
        A[q] = *(const f4*)(hebb + 4 * k[q]);   // always in-bounds (4*NQK = NELEM-4)
    }
    __builtin_amdgcn_sched_barrier(0);

    f4 B[4];
#pragma unroll
    for (int q = 0; q < 4; ++q) {
        B[q].x = __shfl_down(A[q].x, 1, 64);
        B[q].y = __shfl_down(A[q].y, 1, 64);
        B[q].z = __shfl_down(A[q].z, 1, 64);
        B[q].w = 0.f;
    }
    if (lane == 63) {
#pragma unroll
        for (int q = 0; q < 4; ++q)
            if (ok[q]) B[q] = *(const f4*)(hebb + 4 * (k[q] + 1));
    }

#pragma unroll
    for (int q = 0; q < 4; ++q) {
        if (ok[q]) {
            const size_t s = 4 * k[q] + 3;
            const float b[4] = {A[q].w, B[q].x, B[q].y, B[q].z};
            f4 v;
#pragma unroll
            for (int kk = 0; kk < 4; ++kk) {
                const size_t m = s + (size_t)kk;
                const int i = (int)(m >> 12);
                const int jj = (int)(m & (HDIM - 1));
                v[kk] = om * b[kk] + e * hidden[i] * h_f[jj];
            }
            __builtin_nontemporal_store(v, (f4*)(hebb_out + s));  // 16B-aligned
        }
    }
}

extern "C" void kernel_launch(void* const* d_in, const int* in_sizes, int n_in,
                              void* d_out, int out_size, void* d_ws, size_t ws_size,
                              hipStream_t stream) {
    const float* x      = (const float*)d_in[0];
    const float* hidden = (const float*)d_in[1];
    const float* hebb   = (const float*)d_in[2];
    const float* i2h_w  = (const float*)d_in[3];
    const float* i2h_b  = (const float*)d_in[4];
    const float* w      = (const float*)d_in[5];
    const float* alpha  = (const float*)d_in[6];
    const float* eta    = (const float*)d_in[7];
    const float* h2o_w  = (const float*)d_in[8];
    const float* h2o_b  = (const float*)d_in[9];
    const float* h2v_w  = (const float*)d_in[10];
    const float* h2v_b  = (const float*)d_in[11];
    float* out = (float*)d_out;

    // out layout: activout[4] | valueout[1] | h[4096] | hebb_new[4096*4096]
    float* h_out    = out + 5;
    float* hebb_out = out + 5 + HDIM;

    // partial[NCHUNK][HDIM] (16 MB) in the hebb_out region as scratch:
    // consumed by k_hact, then fully overwritten by k_hebb (R3/R7/R8-proven).
    float* partial = out + 8192;

    float* h_f  = (float*)d_ws;        // HDIM floats
    float* acc5 = h_f + HDIM;          // 8 floats (5 used)
    unsigned* cnt = (unsigned*)(acc5 + 8);

    k_matvec<<<dim3(BXC, NCHUNK), TB, 0, stream>>>(w, alpha, hebb, hidden, partial, acc5, cnt);
    k_hact<<<HDIM / HC, TB, 0, stream>>>(partial, x, i2h_w, i2h_b, h2o_w, h2o_b,
                                         h2v_w, h2v_b, h_f, h_out, acc5, cnt, out);
    k_hebb<<<HEB_BLK, TB, 0, stream>>>(hebb, hidden, h_f, eta, hebb_out);
}

// Round 11
// 260.688 us; speedup vs baseline: 1.0262x; 1.0262x over previous
//
#include <hip/hip_runtime.h>
#include <hip/hip_cooperative_groups.h>

namespace cg = cooperative_groups;

#define HDIM 4096
#define NIN 17
#define NA 4

using f4 = __attribute__((ext_vector_type(4))) float;

constexpr int TB = 256;
constexpr size_t NELEM = (size_t)HDIM * HDIM;

// ---- coop config: 1024 blocks (4/CU) x 256 threads ----
constexpr int BXC = 4;                  // column groups (1024 cols each)
constexpr int NCH = 256;                // row chunks
constexpr int RPC = HDIM / NCH;         // 16 rows per block

// ============================================================================
// Cooperative fused kernel with REGISTER-RETAINED hebb.
// Block (bx,by): cols [1024bx,+1024) x rows [16by,+16). Thread: 4 cols x 16 rows.
// Phase 1: matvec partials; hebb -> bv[16] (64 VGPR), ASM-PINNED so the
//          compiler cannot sink/reload them (R2's failure mode).
//          w/alpha NONTEMPORAL (keeps hebb L3-resident across iterations,
//          R3/R7-proven: FETCH = w+alpha = 98 MB only).
// sync -> Phase 2: reduce partial -> h (4 cols/block) + head-dot atomics.
// sync -> Phase 3: hebb_new FROM REGISTERS (zero re-read); per-row LDS shift
//          stage -> aligned NT float4 stores on the 4t+3 grid. Block 0
//          finalizes softmax+value.
// ============================================================================
__global__ __launch_bounds__(TB, 4)
void k_all(const float* __restrict__ w, const float* __restrict__ alpha,
           const float* __restrict__ hebb, const float* __restrict__ hidden,
           const float* __restrict__ x, const float* __restrict__ i2h_w,
           const float* __restrict__ i2h_b,
           const float* __restrict__ h2o_w, const float* __restrict__ h2o_b,
           const float* __restrict__ h2v_w, const float* __restrict__ h2v_b,
           const float* __restrict__ eta,
           float* __restrict__ partial, float* __restrict__ out,
           float* __restrict__ acc5) {
    const int tid = threadIdx.x;
    const int bx = blockIdx.x;            // 0..3
    const int by = blockIdx.y;            // 0..255
    const int col0 = (bx * TB + tid) * 4; // this thread's 4 cols
    const int row0 = by * RPC;

    if (bx == 0 && by == 0 && tid < 8) acc5[tid] = 0.f;  // atomics run after sync1

    // ---------------- phase 1: matvec + hebb into registers -----------------
    f4 bv[RPC];
    f4 acc = {0.f, 0.f, 0.f, 0.f};
#pragma unroll
    for (int p = 0; p < RPC / 4; ++p) {   // 4-row bursts (R7-proven MLP shape)
        f4 wv[4], av[4];
#pragma unroll
        for (int rr = 0; rr < 4; ++rr) {
            const int r = p * 4 + rr;
            const size_t off = (size_t)(row0 + r) * HDIM + col0;
            wv[rr] = __builtin_nontemporal_load((const f4*)(w + off));
            av[rr] = __builtin_nontemporal_load((const f4*)(alpha + off));
            bv[p * 4 + rr] = *(const f4*)(hebb + off);
        }
#pragma unroll
        for (int rr = 0; rr < 4; ++rr) {
            const int r = p * 4 + rr;
            acc += hidden[row0 + r] * (wv[rr] + av[rr] * bv[p * 4 + rr]);
        }
    }
    // Opaque pin: post-asm values can't be re-derived from memory -> the
    // compiler must keep all 64 VGPRs live across the grid syncs.
#pragma unroll
    for (int r = 0; r < RPC; ++r)
        asm volatile("" : "+v"(bv[r].x), "+v"(bv[r].y), "+v"(bv[r].z), "+v"(bv[r].w));

    *(f4*)(partial + (size_t)by * HDIM + col0) = acc;

    cg::this_grid().sync();

    // ---------------- phase 2: reduce -> h + head dots ----------------------
    // flat block id owns 4 columns; thread t reduces chunk t.
    __shared__ f4 red[TB];                // 4 KB
    const int flat = by * BXC + bx;       // 0..1023
    const int j0 = flat * 4;
    red[tid] = *(const f4*)(partial + (size_t)tid * HDIM + j0);
    __syncthreads();
    for (int s = TB / 2; s > 0; s >>= 1) {
        if (tid < s) red[tid] += red[tid + s];
        __syncthreads();
    }
    if (tid < 4) {
        const int j = j0 + tid;
        float z = red[0][tid] + i2h_b[j];
#pragma unroll
        for (int k = 0; k < NIN; ++k) z += x[k] * i2h_w[j * NIN + k];
        const float h = tanhf(z);
        out[5 + j] = h;
        float d[NA + 1];
#pragma unroll
        for (int a = 0; a < NA; ++a) d[a] = h * h2o_w[(size_t)a * HDIM + j];
        d[NA] = h * h2v_w[j];
#pragma unroll
        for (int a = 0; a <= NA; ++a) {
            float v = d[a];
            v += __shfl_down(v, 2, 4);
            v += __shfl_down(v, 1, 4);
            if (tid == 0) atomicAdd(acc5 + a, v);
        }
    }

    cg::this_grid().sync();

    // ---------------- softmax/value finalize (block 0, overlaps phase 3) ----
    if (bx == 0 && by == 0 && tid == 0) {
        float res[NA + 1];
#pragma unroll
        for (int a = 0; a <= NA; ++a) res[a] = atomicAdd(acc5 + a, 0.f);
        float o[NA];
        float mx = -1e30f;
#pragma unroll
        for (int a = 0; a < NA; ++a) { o[a] = res[a] + h2o_b[a]; mx = fmaxf(mx, o[a]); }
        float se = 0.f;
#pragma unroll
        for (int a = 0; a < NA; ++a) { o[a] = __expf(o[a] - mx); se += o[a]; }
#pragma unroll
        for (int a = 0; a < NA; ++a) out[a] = o[a] / se;
        out[NA] = res[NA] + h2v_b[0];
    }

    // ---------------- phase 3: hebb_new from registers ----------------------
    // This thread's h values (written by some block in phase 2; L2/L3-hot).
    const f4 hv4 = *(const f4*)(out + 5 + col0);
    const float e = eta[0];
    const float om = 1.f - e;

    // Per row: stage the block's 1024 values in LDS, then store aligned
    // 16B quads on the 4t+3 grid (out+4101+span ≡ 1 mod 4 -> +3 aligns).
    __shared__ f4 sh[2][TB + 1];          // double buffer: 1 barrier per row
    float* __restrict__ hebb_out = out + 5 + HDIM;   // element offset 4101
#pragma unroll 2
    for (int r = 0; r < RPC; ++r) {
        const int row = row0 + r;
        const f4 val = om * bv[r] + (e * hidden[row]) * hv4;
        f4* sb = sh[r & 1];
        sb[tid] = val;
        __syncthreads();
        float* base = hebb_out + (size_t)row * HDIM + bx * 1024;
        if (tid < TB - 1) {
            // quad t covers span positions 4t+3 .. 4t+6
            const f4 v = {sb[tid].w, sb[tid + 1].x, sb[tid + 1].y, sb[tid + 1].z};
            __builtin_nontemporal_store(v, (f4*)(base + 4 * tid + 3));
        } else {
            // leftovers: positions 0,1,2 and 1023
            __builtin_nontemporal_store(sb[0].x, base + 0);
            __builtin_nontemporal_store(sb[0].y, base + 1);
            __builtin_nontemporal_store(sb[0].z, base + 2);
            __builtin_nontemporal_store(sb[TB - 1].w, base + 1023);
        }
    }
}

// ============================================================================
// Fallback: R7's proven 3-kernel path (bench 258.8).
// ============================================================================
constexpr int FBXC = 4;
constexpr int FNCHUNK = 1024;
constexpr int FRPC = 4;

__global__ void k_matvec(const float* __restrict__ w, const float* __restrict__ alpha,
                         const float* __restrict__ hebb, const float* __restrict__ hidden,
                         float* __restrict__ partial, float* __restrict__ acc5,
                         unsigned* __restrict__ cnt) {
    if (blockIdx.x == 0 && blockIdx.y == 0 && threadIdx.x < 9) {
        if (threadIdx.x < 8) acc5[threadIdx.x] = 0.f;
        else *cnt = 0u;
    }
    const int col0 = (blockIdx.x * TB + threadIdx.x) * 4;
    const int row0 = blockIdx.y * FRPC;
    const size_t base = (size_t)row0 * HDIM + col0;
    f4 wv[FRPC], av[FRPC], bv[FRPC];
#pragma unroll
    for (int r = 0; r < FRPC; ++r) {
        const size_t off = base + (size_t)r * HDIM;
        wv[r] = __builtin_nontemporal_load((const f4*)(w + off));
        av[r] = __builtin_nontemporal_load((const f4*)(alpha + off));
        bv[r] = *(const f4*)(hebb + off);
    }
    f4 acc = {0.f, 0.f, 0.f, 0.f};
#pragma unroll
    for (int r = 0; r < FRPC; ++r) acc += hidden[row0 + r] * (wv[r] + av[r] * bv[r]);
    *(f4*)(partial + (size_t)blockIdx.y * HDIM + col0) = acc;
}

constexpr int HC = 32;
constexpr int HGRP = TB / HC;
constexpr int HCPG = FNCHUNK / HGRP;

__global__ void k_hact(const float* __restrict__ partial, const float* __restrict__ x,
                       const float* __restrict__ i2h_w, const float* __restrict__ i2h_b,
                       const float* __restrict__ h2o_w, const float* __restrict__ h2o_b,
                       const float* __restrict__ h2v_w, const float* __restrict__ h2v_b,
                       float* __restrict__ h_f, float* __restrict__ h_out,
                       float* __restrict__ acc5, unsigned* __restrict__ cnt,
                       float* __restrict__ out) {
    const int tid = threadIdx.x;
    const int lane = tid & (HC - 1);
    const int grp = tid >> 5;
    const int col = blockIdx.x * HC + lane;
    float s = 0.f;
    const float* p = partial + (size_t)(grp * HCPG) * HDIM + col;
#pragma unroll 16
    for (int c = 0; c < HCPG; ++c) s += p[(size_t)c * HDIM];
    __shared__ float red[TB];
    red[tid] = s;
    __syncthreads();
    for (int st = TB / 2; st >= HC; st >>= 1) {
        if (tid < st) red[tid] += red[tid + st];
        __syncthreads();
    }
    if (tid < HC) {
        float z = red[tid] + i2h_b[col];
#pragma unroll
        for (int k = 0; k < NIN; ++k) z += x[k] * i2h_w[col * NIN + k];
        const float h = tanhf(z);
        h_f[col] = h;
        h_out[col] = h;
        float d[NA + 1];
#pragma unroll
        for (int a = 0; a < NA; ++a) d[a] = h * h2o_w[(size_t)a * HDIM + col];
        d[NA] = h * h2v_w[col];
#pragma unroll
        for (int a = 0; a <= NA; ++a) {
            float v = d[a];
#pragma unroll
            for (int sft = 16; sft > 0; sft >>= 1) v += __shfl_down(v, sft, 32);
            if (lane == 0) atomicAdd(acc5 + a, v);
        }
    }
    if (tid == 0) {
        __threadfence();
        if (atomicAdd(cnt, 1u) == (HDIM / HC) - 1) {
            float res[NA + 1];
#pragma unroll
            for (int a = 0; a <= NA; ++a) res[a] = atomicAdd(acc5 + a, 0.f);
            float o[NA];
            float mx = -1e30f;
#pragma unroll
            for (int a = 0; a < NA; ++a) { o[a] = res[a] + h2o_b[a]; mx = fmaxf(mx, o[a]); }
            float se = 0.f;
#pragma unroll
            for (int a = 0; a < NA; ++a) { o[a] = __expf(o[a] - mx); se += o[a]; }
#pragma unroll
            for (int a = 0; a < NA; ++a) out[a] = o[a] / se;
            out[NA] = res[NA] + h2v_b[0];
        }
    }
}

constexpr size_t NQK = (NELEM - 4) / 4;
constexpr int HEB_BLK = 4096;

__global__ void k_hebb(const float* __restrict__ hebb, const float* __restrict__ hidden,
                       const float* __restrict__ h_f, const float* __restrict__ eta,
                       float* __restrict__ hebb_out) {
    const int tid = threadIdx.x;
    const size_t gt = (size_t)blockIdx.x * TB + tid;
    const size_t wid = gt >> 6;
    const int lane = tid & 63;
    const float e = eta[0];
    const float om = 1.f - e;
    if (gt == 0) {
        const float hv0 = e * hidden[0];
        hebb_out[0] = om * hebb[0] + hv0 * h_f[0];
        hebb_out[1] = om * hebb[1] + hv0 * h_f[1];
        hebb_out[2] = om * hebb[2] + hv0 * h_f[2];
        hebb_out[NELEM - 1] = om * hebb[NELEM - 1] + e * hidden[HDIM - 1] * h_f[HDIM - 1];
    }
    size_t k[4]; bool ok[4]; f4 A[4];
#pragma unroll
    for (int q = 0; q < 4; ++q) {
        k[q] = wid * 256 + (size_t)lane + (size_t)q * 64;
        ok[q] = k[q] < NQK;
        A[q] = *(const f4*)(hebb + 4 * k[q]);
    }
    __builtin_amdgcn_sched_barrier(0);
    f4 B[4];
#pragma unroll
    for (int q = 0; q < 4; ++q) {
        B[q].x = __shfl_down(A[q].x, 1, 64);
        B[q].y = __shfl_down(A[q].y, 1, 64);
        B[q].z = __shfl_down(A[q].z, 1, 64);
        B[q].w = 0.f;
    }
    if (lane == 63) {
#pragma unroll
        for (int q = 0; q < 4; ++q)
            if (ok[q]) B[q] = *(const f4*)(hebb + 4 * (k[q] + 1));
    }
#pragma unroll
    for (int q = 0; q < 4; ++q) {
        if (ok[q]) {
            const size_t s = 4 * k[q] + 3;
            const float b[4] = {A[q].w, B[q].x, B[q].y, B[q].z};
            f4 v;
#pragma unroll
            for (int kk = 0; kk < 4; ++kk) {
                const size_t m = s + (size_t)kk;
                const int i = (int)(m >> 12);
                const int jj = (int)(m & (HDIM - 1));
                v[kk] = om * b[kk] + e * hidden[i] * h_f[jj];
            }
            __builtin_nontemporal_store(v, (f4*)(hebb_out + s));
        }
    }
}

extern "C" void kernel_launch(void* const* d_in, const int* in_sizes, int n_in,
                              void* d_out, int out_size, void* d_ws, size_t ws_size,
                              hipStream_t stream) {
    const float* x      = (const float*)d_in[0];
    const float* hidden = (const float*)d_in[1];
    const float* hebb   = (const float*)d_in[2];
    const float* i2h_w  = (const float*)d_in[3];
    const float* i2h_b  = (const float*)d_in[4];
    const float* w      = (const float*)d_in[5];
    const float* alpha  = (const float*)d_in[6];
    const float* eta    = (const float*)d_in[7];
    const float* h2o_w  = (const float*)d_in[8];
    const float* h2o_b  = (const float*)d_in[9];
    const float* h2v_w  = (const float*)d_in[10];
    const float* h2v_b  = (const float*)d_in[11];
    float* out = (float*)d_out;

    float* h_out    = out + 5;
    float* hebb_out = out + 5 + HDIM;

    // coop path workspace: partial[256][4096] = 4 MB + acc5
    float* partial = (float*)d_ws;
    float* acc5 = partial + (size_t)NCH * HDIM;
    unsigned* cnt = (unsigned*)(acc5 + 8);

    static int coop = -1;
    if (coop < 0) {
        int maxb = 0;
        hipError_t err = hipOccupancyMaxActiveBlocksPerMultiprocessor(&maxb, k_all, TB, 0);
        coop = (err == hipSuccess && maxb >= 4) ? 1 : 0;
    }

    if (coop) {
        void* args[] = {(void*)&w, (void*)&alpha, (void*)&hebb, (void*)&hidden,
                        (void*)&x, (void*)&i2h_w, (void*)&i2h_b,
                        (void*)&h2o_w, (void*)&h2o_b, (void*)&h2v_w, (void*)&h2v_b,
                        (void*)&eta, (void*)&partial, (void*)&out, (void*)&acc5};
        hipLaunchCooperativeKernel(k_all, dim3(BXC, NCH), dim3(TB), args, 0, stream);
    } else {
        // fallback: R7 path; its 16 MB partial lives in the hebb_out region
        float* fpartial = out + 8192;
        float* h_f = acc5 + 16;
        k_matvec<<<dim3(FBXC, FNCHUNK), TB, 0, stream>>>(w, alpha, hebb, hidden, fpartial, acc5, cnt);
        k_hact<<<HDIM / HC, TB, 0, stream>>>(fpartial, x, i2h_w, i2h_b, h2o_w, h2o_b,
                                             h2v_w, h2v_b, h_f, h_out, acc5, cnt, out);
        k_hebb<<<HEB_BLK, TB, 0, stream>>>(hebb, hidden, h_f, eta, hebb_out);
    }
}